// Round 4
// baseline (693.520 us; speedup 1.0000x reference)
//
#include <hip/hip_runtime.h>

typedef int v4i  __attribute__((ext_vector_type(4)));
typedef int v16i __attribute__((ext_vector_type(16)));

#define TT 1024
#define DD 256
#define HH 512
#define CB 32
#define CM (CB*TT)   // 32768 rows per chunk

__device__ __forceinline__ double shfl_xor_d(double x, int m) {
    union { double d; int u[2]; } a; a.d = x;
    a.u[0] = __shfl_xor(a.u[0], m);
    a.u[1] = __shfl_xor(a.u[1], m);
    return a.d;
}

// ---------------------------------------------------------------------------
// prep_w: split W1 [512][256] and W2 [256][512] into 5 signed-digit i8 planes.
// w = sum_j d_j * 2^(-10-7j), truncation digits, |d|<=127. Row-major kept.
// ---------------------------------------------------------------------------
__global__ __launch_bounds__(256) void prep_w_k(const float* __restrict__ W1,
                                                const float* __restrict__ W2,
                                                signed char* __restrict__ W1p,
                                                signed char* __restrict__ W2p) {
    int i = blockIdx.x * 256 + threadIdx.x;   // 0..131071
    {
        double a = (double)W1[i];
        double inv = 1024.0, s = 1.0 / 1024.0;
#pragma unroll
        for (int p = 0; p < 5; ++p) {
            int d = (int)(a * inv);
            a -= d * s;
            W1p[(size_t)p * 131072 + i] = (signed char)d;
            inv *= 128.0; s *= (1.0 / 128.0);
        }
    }
    {
        double a = (double)W2[i];
        double inv = 1024.0, s = 1.0 / 1024.0;
#pragma unroll
        for (int p = 0; p < 5; ++p) {
            int d = (int)(a * inv);
            a -= d * s;
            W2p[(size_t)p * 131072 + i] = (signed char)d;
            inv *= 128.0; s *= (1.0 / 128.0);
        }
    }
}

// ---------------------------------------------------------------------------
// GEMM1: H = x @ W1^T + b1 -> LayerNorm(512). Exact Ozaki i8 (15 pairs,
// 5 i32 banks). A: x split to 5 digit planes IN-KERNEL (exact f32 ops),
// staged once in LDS (swizzled). B: direct global->VGPR (L2-resident W1p),
// 1-step register prefetch. One barrier for staging, no K-loop barriers.
// Block 32 rows x 512 cols, 512 thr = 8 waves (1m x 8n), wave tile 32x64.
// ---------------------------------------------------------------------------
__global__ __launch_bounds__(512, 2) void gemm1_i8(
    const float* __restrict__ X, const signed char* __restrict__ W1p,
    const float* __restrict__ b1, const float* __restrict__ g1,
    const float* __restrict__ be1, double* __restrict__ Hn) {
    __shared__ signed char Asm[5 * 8192];       // 40960 B
    __shared__ double RS[8][32], RQ[8][32];
    __shared__ double MUs[32], IVs[32];

    const int tid = threadIdx.x;
    const int wave = tid >> 6, lane = tid & 63, lrow = lane & 31, lhalf = lane >> 5;
    const int m0 = blockIdx.x * 32;

    // ---- A stage: load x tile [32][256] f32, split to 5 i8 planes ----
    {
        const int r = tid >> 4;             // 0..31
        const int k0 = (tid & 15) * 16;     // element/byte offset in row
        const float* xp = X + (size_t)(m0 + r) * DD + k0;
        float xe[16];
        *(float4*)(xe + 0)  = *(const float4*)(xp + 0);
        *(float4*)(xe + 4)  = *(const float4*)(xp + 4);
        *(float4*)(xe + 8)  = *(const float4*)(xp + 8);
        *(float4*)(xe + 12) = *(const float4*)(xp + 12);
        int pk[5][4];
#pragma unroll
        for (int q = 0; q < 4; ++q)
#pragma unroll
            for (int e = 0; e < 4; ++e) {
                float a = xe[q * 4 + e];
                float inv = 8.0f, s = 0.125f;
#pragma unroll
                for (int p = 0; p < 5; ++p) {
                    int d = (int)(a * inv);       // exact: pow2 scale + trunc
                    a -= (float)d * s;            // exact cancellation
                    int byte = (d & 255) << (8 * e);
                    if (e == 0) pk[p][q] = byte; else pk[p][q] |= byte;
                    inv *= 128.0f; s *= (1.0f / 128.0f);
                }
            }
        const int swz = k0 ^ ((r & 7) << 4);
#pragma unroll
        for (int p = 0; p < 5; ++p)
            *(v4i*)&Asm[p * 8192 + r * 256 + swz] = *(const v4i*)pk[p];
    }

    v16i acc[5][2];
#pragma unroll
    for (int g = 0; g < 5; ++g)
#pragma unroll
        for (int nt = 0; nt < 2; ++nt)
#pragma unroll
            for (int r = 0; r < 16; ++r) acc[g][nt][r] = 0;

    // per-lane B base pointers (nt = 0/1)
    const signed char* bb[2];
    bb[0] = W1p + (size_t)(wave * 64 + lrow) * 256 + lhalf * 16;
    bb[1] = bb[0] + 32 * 256;

    v4i cb[2][2];   // current B frags [nt][ks]
#pragma unroll
    for (int nt = 0; nt < 2; ++nt)
#pragma unroll
        for (int ks = 0; ks < 2; ++ks)
            cb[nt][ks] = *(const v4i*)(bb[nt] + ks * 32);

    __syncthreads();   // A ready

    const int aswz = (lrow & 7) << 4;
#pragma unroll
    for (int j = 0; j < 5; ++j)
#pragma unroll
        for (int kk = 0; kk < 4; ++kk) {
            const int it = j * 4 + kk;
            v4i nb[2][2];
            if (it < 19) {
                const int nj = (kk == 3) ? j + 1 : j;
                const int nkk = (kk == 3) ? 0 : kk + 1;
                const size_t off = (size_t)nj * 131072 + nkk * 64;
#pragma unroll
                for (int nt = 0; nt < 2; ++nt)
#pragma unroll
                    for (int ks = 0; ks < 2; ++ks)
                        nb[nt][ks] = *(const v4i*)(bb[nt] + off + ks * 32);
            }
#pragma unroll
            for (int i = 0; i + j < 5; ++i) {
                v4i a0 = *(const v4i*)&Asm[i * 8192 + lrow * 256 +
                                           ((kk * 64 + lhalf * 16) ^ aswz)];
                v4i a1 = *(const v4i*)&Asm[i * 8192 + lrow * 256 +
                                           ((kk * 64 + 32 + lhalf * 16) ^ aswz)];
                acc[i + j][0] = __builtin_amdgcn_mfma_i32_32x32x32_i8(a0, cb[0][0], acc[i + j][0], 0, 0, 0);
                acc[i + j][0] = __builtin_amdgcn_mfma_i32_32x32x32_i8(a1, cb[0][1], acc[i + j][0], 0, 0, 0);
                acc[i + j][1] = __builtin_amdgcn_mfma_i32_32x32x32_i8(a0, cb[1][0], acc[i + j][1], 0, 0, 0);
                acc[i + j][1] = __builtin_amdgcn_mfma_i32_32x32x32_i8(a1, cb[1][1], acc[i + j][1], 0, 0, 0);
            }
#pragma unroll
            for (int nt = 0; nt < 2; ++nt)
#pragma unroll
                for (int ks = 0; ks < 2; ++ks)
                    cb[nt][ks] = nb[nt][ks];
        }

    // ---- epilogue: exact recombine -> fp64, bias, LayerNorm, store ----
    const double scl[5] = {0x1p-13, 0x1p-20, 0x1p-27, 0x1p-34, 0x1p-41};
    double vv[2][16];
    int colc[2];
#pragma unroll
    for (int nt = 0; nt < 2; ++nt) {
        colc[nt] = wave * 64 + nt * 32 + lrow;
        double bcol = (double)b1[colc[nt]];
#pragma unroll
        for (int r = 0; r < 16; ++r) {
            double t = 0.0;
#pragma unroll
            for (int g = 0; g < 5; ++g) t = fma((double)acc[g][nt][r], scl[g], t);
            vv[nt][r] = t + bcol;
        }
    }
    double ps[16], pq[16];
#pragma unroll
    for (int r = 0; r < 16; ++r) {
        ps[r] = vv[0][r] + vv[1][r];
        pq[r] = vv[0][r] * vv[0][r] + vv[1][r] * vv[1][r];
    }
#pragma unroll
    for (int m = 1; m < 32; m <<= 1)
#pragma unroll
        for (int r = 0; r < 16; ++r) {
            ps[r] += shfl_xor_d(ps[r], m);
            pq[r] += shfl_xor_d(pq[r], m);
        }
    if (lrow == 0) {
#pragma unroll
        for (int r = 0; r < 16; ++r) {
            int rw = (r & 3) + 8 * (r >> 2) + 4 * lhalf;
            RS[wave][rw] = ps[r];
            RQ[wave][rw] = pq[r];
        }
    }
    __syncthreads();
    if (tid < 32) {
        double s = 0.0, q = 0.0;
#pragma unroll
        for (int w = 0; w < 8; ++w) { s += RS[w][tid]; q += RQ[w][tid]; }
        double mu = s * (1.0 / 512.0);
        double var = q * (1.0 / 512.0) - mu * mu;
        MUs[tid] = mu;
        IVs[tid] = 1.0 / sqrt(var + 1e-5);
    }
    __syncthreads();
#pragma unroll
    for (int nt = 0; nt < 2; ++nt) {
        int col = colc[nt];
        double gg = (double)g1[col], bb2 = (double)be1[col];
#pragma unroll
        for (int r = 0; r < 16; ++r) {
            int rw = (r & 3) + 8 * (r >> 2) + 4 * lhalf;
            double o = (vv[nt][r] - MUs[rw]) * IVs[rw] * gg + bb2;
            Hn[(size_t)(m0 + rw) * 512 + col] = o;
        }
    }
}

// ---------------------------------------------------------------------------
// GEMM2: Y = S @ W2^T + b2 -> LayerNorm(256). A = spikes (single exact
// plane) staged once in LDS; B = 5 W2 planes direct global->VGPR w/ prefetch.
// Block 64 x 256, 512 thr = 8 waves (2m x 4n), wave tile 32x64.
// ---------------------------------------------------------------------------
__global__ __launch_bounds__(512, 2) void gemm2_i8(
    const signed char* __restrict__ S, const signed char* __restrict__ W2p,
    const float* __restrict__ b2, const float* __restrict__ g2,
    const float* __restrict__ be2, double* __restrict__ Yn) {
    __shared__ signed char Asm[64 * 512];       // 32768 B
    __shared__ double RS[4][64], RQ[4][64];
    __shared__ double MUs[64], IVs[64];

    const int tid = threadIdx.x;
    const int wave = tid >> 6, lane = tid & 63, lrow = lane & 31, lhalf = lane >> 5;
    const int wm = wave >> 2, wn = wave & 3;
    const int m0 = blockIdx.x * 64;

    // ---- A stage: spikes [64][512] ----
    {
        const int r = tid >> 3, k0 = (tid & 7) * 64;
#pragma unroll
        for (int q = 0; q < 4; ++q) {
            int k = k0 + q * 16;
            v4i v = *(const v4i*)(S + (size_t)(m0 + r) * 512 + k);
            *(v4i*)&Asm[r * 512 + (k ^ ((r & 7) << 4))] = v;
        }
    }

    v16i acc[5][2];
#pragma unroll
    for (int g = 0; g < 5; ++g)
#pragma unroll
        for (int nt = 0; nt < 2; ++nt)
#pragma unroll
            for (int r = 0; r < 16; ++r) acc[g][nt][r] = 0;

    const signed char* bb[2];
    bb[0] = W2p + (size_t)(wn * 64 + lrow) * 512 + lhalf * 16;
    bb[1] = bb[0] + 32 * 512;

    v4i cb[2][4];
#pragma unroll
    for (int nt = 0; nt < 2; ++nt)
#pragma unroll
        for (int ks = 0; ks < 4; ++ks)
            cb[nt][ks] = *(const v4i*)(bb[nt] + ks * 32);

    __syncthreads();

    const int arow = wm * 32 + lrow;
    const int aswz = (arow & 7) << 4;
#pragma unroll
    for (int j = 0; j < 5; ++j)
#pragma unroll
        for (int kk = 0; kk < 4; ++kk) {
            const int it = j * 4 + kk;
            v4i nb[2][4];
            if (it < 19) {
                const int nj = (kk == 3) ? j + 1 : j;
                const int nkk = (kk == 3) ? 0 : kk + 1;
                const size_t off = (size_t)nj * 131072 + nkk * 128;
#pragma unroll
                for (int nt = 0; nt < 2; ++nt)
#pragma unroll
                    for (int ks = 0; ks < 4; ++ks)
                        nb[nt][ks] = *(const v4i*)(bb[nt] + off + ks * 32);
            }
#pragma unroll
            for (int ks = 0; ks < 4; ++ks) {
                v4i a = *(const v4i*)&Asm[arow * 512 +
                                          ((kk * 128 + ks * 32 + lhalf * 16) ^ aswz)];
                acc[j][0] = __builtin_amdgcn_mfma_i32_32x32x32_i8(a, cb[0][ks], acc[j][0], 0, 0, 0);
                acc[j][1] = __builtin_amdgcn_mfma_i32_32x32x32_i8(a, cb[1][ks], acc[j][1], 0, 0, 0);
            }
#pragma unroll
            for (int nt = 0; nt < 2; ++nt)
#pragma unroll
                for (int ks = 0; ks < 4; ++ks)
                    cb[nt][ks] = nb[nt][ks];
        }

    const double scl[5] = {0x1p-10, 0x1p-17, 0x1p-24, 0x1p-31, 0x1p-38};
    double vv[2][16];
    int colc[2];
#pragma unroll
    for (int nt = 0; nt < 2; ++nt) {
        colc[nt] = wn * 64 + nt * 32 + lrow;
        double bcol = (double)b2[colc[nt]];
#pragma unroll
        for (int r = 0; r < 16; ++r) {
            double t = 0.0;
#pragma unroll
            for (int g = 0; g < 5; ++g) t = fma((double)acc[g][nt][r], scl[g], t);
            vv[nt][r] = t + bcol;
        }
    }
    double ps[16], pq[16];
#pragma unroll
    for (int r = 0; r < 16; ++r) {
        ps[r] = vv[0][r] + vv[1][r];
        pq[r] = vv[0][r] * vv[0][r] + vv[1][r] * vv[1][r];
    }
#pragma unroll
    for (int m = 1; m < 32; m <<= 1)
#pragma unroll
        for (int r = 0; r < 16; ++r) {
            ps[r] += shfl_xor_d(ps[r], m);
            pq[r] += shfl_xor_d(pq[r], m);
        }
    if (lrow == 0) {
#pragma unroll
        for (int r = 0; r < 16; ++r) {
            int rw = wm * 32 + (r & 3) + 8 * (r >> 2) + 4 * lhalf;
            RS[wn][rw] = ps[r];
            RQ[wn][rw] = pq[r];
        }
    }
    __syncthreads();
    if (tid < 64) {
        double s = 0.0, q = 0.0;
#pragma unroll
        for (int w = 0; w < 4; ++w) { s += RS[w][tid]; q += RQ[w][tid]; }
        double mu = s * (1.0 / 256.0);
        double var = q * (1.0 / 256.0) - mu * mu;
        MUs[tid] = mu;
        IVs[tid] = 1.0 / sqrt(var + 1e-5);
    }
    __syncthreads();
#pragma unroll
    for (int nt = 0; nt < 2; ++nt) {
        int col = colc[nt];
        double gg = (double)g2[col], bb2 = (double)be2[col];
#pragma unroll
        for (int r = 0; r < 16; ++r) {
            int rw = wm * 32 + (r & 3) + 8 * (r >> 2) + 4 * lhalf;
            double o = (vv[nt][r] - MUs[rw]) * IVs[rw] * gg + bb2;
            Yn[(size_t)(m0 + rw) * 256 + col] = o;
        }
    }
}

// ---------------------------------------------------------------------------
// LIF1: fp64 recurrence over T, one lane per (b,h), depth-3 group prefetch.
// ---------------------------------------------------------------------------
__global__ __launch_bounds__(64) void lif1_k(const double* __restrict__ Hn,
                                             signed char* __restrict__ S) {
    int b = blockIdx.x >> 3;
    int h = (blockIdx.x & 7) * 64 + threadIdx.x;
    const double* src = Hn + (size_t)b * TT * HH + h;
    signed char* dst = S + (size_t)b * TT * HH + h;
    double v = 0.0;
    double buf[4][16];
#pragma unroll
    for (int gg = 0; gg < 3; ++gg)
#pragma unroll
        for (int t = 0; t < 16; ++t) buf[gg][t] = src[(size_t)(gg * 16 + t) * HH];
    for (int g4 = 0; g4 < 64; g4 += 4) {
#pragma unroll
        for (int u = 0; u < 4; ++u) {
            int g = g4 + u;
            if (g + 3 < 64) {
#pragma unroll
                for (int t = 0; t < 16; ++t)
                    buf[(u + 3) & 3][t] = src[(size_t)((g + 3) * 16 + t) * HH];
            }
#pragma unroll
            for (int t = 0; t < 16; ++t) {
                v += (buf[u][t] - v) * 0.5;
                bool sp = (v >= 1.0);
                dst[(size_t)(g * 16 + t) * HH] = sp ? 1 : 0;
                if (sp) v = 0.0;
            }
        }
    }
}

// ---------------------------------------------------------------------------
// LIF2 + residual: out = x + spike, fp64 recurrence, depth-3 prefetch.
// ---------------------------------------------------------------------------
__global__ __launch_bounds__(64) void lif2_k(const double* __restrict__ Yn,
                                             const float* __restrict__ X,
                                             float* __restrict__ out) {
    int b = blockIdx.x >> 2;
    int d = (blockIdx.x & 3) * 64 + threadIdx.x;
    const double* src = Yn + (size_t)b * TT * DD + d;
    const float* xs = X + (size_t)b * TT * DD + d;
    float* dst = out + (size_t)b * TT * DD + d;
    double v = 0.0;
    double bufy[4][16];
    float bufx[4][16];
#pragma unroll
    for (int gg = 0; gg < 3; ++gg)
#pragma unroll
        for (int t = 0; t < 16; ++t) {
            bufy[gg][t] = src[(size_t)(gg * 16 + t) * DD];
            bufx[gg][t] = xs[(size_t)(gg * 16 + t) * DD];
        }
    for (int g4 = 0; g4 < 64; g4 += 4) {
#pragma unroll
        for (int u = 0; u < 4; ++u) {
            int g = g4 + u;
            if (g + 3 < 64) {
#pragma unroll
                for (int t = 0; t < 16; ++t) {
                    bufy[(u + 3) & 3][t] = src[(size_t)((g + 3) * 16 + t) * DD];
                    bufx[(u + 3) & 3][t] = xs[(size_t)((g + 3) * 16 + t) * DD];
                }
            }
#pragma unroll
            for (int t = 0; t < 16; ++t) {
                v += (bufy[u][t] - v) * 0.5;
                bool sp = (v >= 1.0);
                dst[(size_t)(g * 16 + t) * DD] = bufx[u][t] + (sp ? 1.0f : 0.0f);
                if (sp) v = 0.0;
            }
        }
    }
}

extern "C" void kernel_launch(void* const* d_in, const int* in_sizes, int n_in,
                              void* d_out, int out_size, void* d_ws, size_t ws_size,
                              hipStream_t stream) {
    const float* x   = (const float*)d_in[0];
    const float* W1  = (const float*)d_in[1];
    const float* b1  = (const float*)d_in[2];
    const float* g1  = (const float*)d_in[3];
    const float* be1 = (const float*)d_in[4];
    const float* W2  = (const float*)d_in[5];
    const float* b2  = (const float*)d_in[6];
    const float* g2  = (const float*)d_in[7];
    const float* be2 = (const float*)d_in[8];
    float* out = (float*)d_out;

    char* ws = (char*)d_ws;
    signed char* W1p = (signed char*)ws;                          // 640 KB
    signed char* W2p = (signed char*)(ws + (1ull << 20));         // 640 KB
    double*      Hn  = (double*)(ws + (2ull << 20));              // 128 MB
    signed char* Sb  = (signed char*)(ws + (130ull << 20));       // 16 MB
    double*      Yn  = (double*)(ws + (146ull << 20));            // 64 MB
    // total 210 MB

    prep_w_k<<<dim3(512), dim3(256), 0, stream>>>(W1, W2, W1p, W2p);

    for (int c = 0; c < 2; ++c) {
        const float* xc = x + (size_t)c * CM * DD;
        float* outc = out + (size_t)c * CM * DD;
        gemm1_i8<<<dim3(CM / 32), dim3(512), 0, stream>>>(xc, W1p, b1, g1, be1, Hn);
        lif1_k<<<dim3(CB * 8), dim3(64), 0, stream>>>(Hn, Sb);
        gemm2_i8<<<dim3(CM / 64), dim3(512), 0, stream>>>(Sb, W2p, b2, g2, be2, Yn);
        lif2_k<<<dim3(CB * 4), dim3(64), 0, stream>>>(Yn, xc, outc);
    }
}